// Round 8
// baseline (400.590 us; speedup 1.0000x reference)
//
#include <hip/hip_runtime.h>

#define HEADS 4
#define NH    256
#define LEN   4096
#define NB    16
#define TT    1024
#define NSUB  4

typedef float     f32x4 __attribute__((ext_vector_type(4)));
typedef float     f32x2 __attribute__((ext_vector_type(2)));
typedef _Float16  f16x8 __attribute__((ext_vector_type(8)));
typedef unsigned  u32x2 __attribute__((ext_vector_type(2)));
typedef unsigned  u32x4 __attribute__((ext_vector_type(4)));

__device__ __forceinline__ unsigned packh(float a, float b) {
    union { _Float16 h[2]; unsigned u; } z;
    z.h[0] = (_Float16)a; z.h[1] = (_Float16)b;
    return z.u;
}
__device__ __forceinline__ unsigned short h16u(float a) {
    union { _Float16 h; unsigned short u; } z;
    z.h = (_Float16)a; return z.u;
}

// ---------------------------------------------------------------------------
// Weight table for A-fragments (verified R7): per (h, c, unit): Prev[y],
// y in [0,128):  Prev[y] = w_u[95 - y] (f16, normalized), zero outside range.
// ---------------------------------------------------------------------------
__global__ __launch_bounds__(64) void build_wgt_kernel(
    const float* __restrict__ kernels, unsigned short* __restrict__ wtab)
{
    const int h    = blockIdx.x;
    const int lane = threadIdx.x;

    float ssum[4] = {0.f, 0.f, 0.f, 0.f};
    #pragma unroll
    for (int q = 0; q < 3; ++q) {
        const int tap = lane + q * 64;
        const int i = tap >> 5;
        const int j = tap & 31;
        const float scale = (float)(1 << (5 - i));
        const float repf  = (float)(i == 0 ? 1 : (1 << (i - 1)));
        #pragma unroll
        for (int c = 0; c < 4; ++c) {
            const float kv = kernels[(((i * HEADS) + c) * NH + h) * 32 + j];
            const float v  = kv * scale;
            ssum[c] += v * v * repf;
        }
    }
    #pragma unroll
    for (int off = 32; off > 0; off >>= 1) {
        #pragma unroll
        for (int c = 0; c < 4; ++c) ssum[c] += __shfl_xor(ssum[c], off);
    }
    float inv[4];
    #pragma unroll
    for (int c = 0; c < 4; ++c) inv[c] = 1.0f / sqrtf(ssum[c]);

    for (int it = 0; it < 40; ++it) {
        const int idx = it * 64 + lane;
        const int c   = idx / 640;
        const int rem = idx - c * 640;
        const int u   = rem >> 7;
        const int y   = rem & 127;
        const int j   = 95 - y;
        const int J   = (u == 0) ? 64 : 32;
        float val = 0.f;
        if (j >= 0 && j < J) {
            int s, tp;
            if (u == 0) { s = (j < 32) ? 0 : 1; tp = j & 31; }
            else        { s = u + 1;            tp = j;      }
            val = kernels[((s * HEADS + c) * NH + h) * 32 + tp]
                  * (float)(1 << (5 - s)) * inv[c];
        }
        wtab[((h * 4 + c) * 5 + u) * 128 + y] = h16u(val);
    }
}

// ---------------------------------------------------------------------------
// MFMA conv kernel (structure verified R7).  Grid (2 cpair, 256 h, 16 b),
// 256 threads (4 waves).  Epilogue D-scratch re-strided to 5 floats/row
// (bank = (5*row+e)%32, conflict-free since 5 is invertible mod 32).
// ---------------------------------------------------------------------------
#define G1O   0
#define G2O   2080
#define G4O   4128
#define G8O   6176
#define G16O  8224
#define GTOT  10272
#define SMBYTES 25600        // max(GTOT*2 = 20544, 1280 rows * 5 f32 * 4)

#define MFMA16(acc, a, bb) \
    (acc) = __builtin_amdgcn_mfma_f32_16x16x32_f16((a), (bb), (acc), 0, 0, 0)

__global__ __launch_bounds__(256, 4) void conv_kernel(
    const float*           __restrict__ x,
    const unsigned short*  __restrict__ wtab,
    const float*           __restrict__ Dp,
    float*                 __restrict__ out)
{
    __shared__ __align__(16) unsigned char SM[SMBYTES];
    unsigned short* G  = (unsigned short*)SM;
    float*          DR = (float*)SM;

    const int cpair = blockIdx.x;
    const int h     = blockIdx.y;
    const int b     = blockIdx.z;
    const int tid   = threadIdx.x;
    const int w     = tid >> 6;
    const int lane  = tid & 63;
    const int dd    = lane & 15;
    const int qq    = lane >> 4;

    const float* xrow = x + ((size_t)(b * NH + h)) * LEN;

    // ---- A-fragments: 22 x f16x8 from global ushort loads ----
    f16x8 AF[22];
    #pragma unroll
    for (int cc = 0; cc < 2; ++cc) {
        const int c = cpair * 2 + cc;
        const unsigned short* wpc = wtab + (size_t)((h * 4 + c) * 5) * 128;
        #pragma unroll
        for (int u = 0; u < 5; ++u) {
            const int J   = (u == 0) ? 64 : 32;
            const int nM  = (u == 0) ? 3 : 2;
            const int bse = (u == 0) ? 0 : (2 * u + 1);
            const unsigned short* wp = wpc + u * 128;
            #pragma unroll
            for (int m = 0; m < 3; ++m) {
                if (m < nM) {
                    const int y0 = 95 - dd - J + 32 * m + 8 * qq;
                    u32x4 dw;
                    #pragma unroll
                    for (int d = 0; d < 4; ++d)
                        dw[d] = (unsigned)wp[y0 + 2 * d]
                              | ((unsigned)wp[y0 + 2 * d + 1] << 16);
                    AF[cc * 11 + bse + m] = __builtin_bit_cast(f16x8, dw);
                }
            }
        }
    }

    const float dC0 = Dp[(cpair * 2 + 0) * NH + h];
    const float dC1 = Dp[(cpair * 2 + 1) * NH + h];

    // ---- B-fragment base element addresses per unit ----
    const int kap = 16 * w + dd;
    const int e0 = G1O  + 16 * kap + 960 + 8 * qq;
    const int e1 = G2O  + (kap & 1)  * 1024 + 16 * (kap >> 1) + 448 + 8 * qq;
    const int e2 = G4O  + (kap & 3)  * 512  + 16 * (kap >> 2) + 192 + 8 * qq;
    const int e3 = G8O  + (kap & 7)  * 256  + 16 * (kap >> 3) + 64  + 8 * qq;
    const int e4 = G16O + (kap & 15) * 128  + 16 * (kap >> 4)       + 8 * qq;

    for (int st = 0; st < NSUB; ++st) {
        const int t0s = st * TT;
        __syncthreads();   // G/D region reuse across subtiles

        // ---- prefix chain (register doubling) + striped f16 G-writes ----
        {
            const int m0 = 8 * tid;
            const int bg = t0s - 544 + m0;
            float v[40];
            #pragma unroll
            for (int blk = 0; blk < 10; ++blk) {
                const int g = bg + 4 * blk;
                f32x4 t;
                if (g >= 0 && g + 3 < LEN) {
                    t = *(const f32x4*)(xrow + g);
                } else {
                    #pragma unroll
                    for (int e = 0; e < 4; ++e) {
                        const int gg = g + e;
                        t[e] = (gg >= 0 && gg < LEN) ? xrow[gg] : 0.f;
                    }
                }
                v[4 * blk] = t.x; v[4 * blk + 1] = t.y;
                v[4 * blk + 2] = t.z; v[4 * blk + 3] = t.w;
            }
            {
                u32x4 px;
                px[0] = packh(v[32], v[33]); px[1] = packh(v[34], v[35]);
                px[2] = packh(v[36], v[37]); px[3] = packh(v[38], v[39]);
                *(u32x4*)&G[G1O + m0] = px;
            }
            if (tid < 4) *(u32x4*)&G[G1O + 2048 + 8 * tid] = (u32x4){0, 0, 0, 0};

            #pragma unroll
            for (int j = 39; j >= 2; --j) v[j] += v[j - 1];      // W2
            #pragma unroll
            for (int ph = 0; ph < 2; ++ph) {
                u32x2 pw;
                pw.x = packh(v[32 + ph], v[34 + ph]);
                pw.y = packh(v[36 + ph], v[38 + ph]);
                *(u32x2*)&G[G2O + ph * 1024 + (m0 >> 1)] = pw;
            }
            #pragma unroll
            for (int j = 39; j >= 4; --j) v[j] += v[j - 2];      // W4
            #pragma unroll
            for (int ph = 0; ph < 4; ++ph)
                *(unsigned*)&G[G4O + ph * 512 + (m0 >> 2)] =
                    packh(v[32 + ph], v[36 + ph]);
            #pragma unroll
            for (int j = 39; j >= 8; --j) v[j] += v[j - 4];      // W8
            #pragma unroll
            for (int e = 0; e < 8; ++e)
                G[G8O + e * 256 + tid] = h16u(v[32 + e]);
            #pragma unroll
            for (int j = 39; j >= 16; --j) v[j] += v[j - 8];     // W16
            #pragma unroll
            for (int e = 0; e < 8; ++e)
                G[G16O + ((m0 & 8) + e) * 128 + (m0 >> 4)] = h16u(v[32 + e]);
        }
        __syncthreads();

        // ---- MFMA phase ----
        f32x4 DA[2][5];
        #pragma unroll
        for (int cc = 0; cc < 2; ++cc)
            #pragma unroll
            for (int u = 0; u < 5; ++u) DA[cc][u] = (f32x4){0.f, 0.f, 0.f, 0.f};

        {   // unit 0 (r=1, K=96)
            const f16x8 b0 = *(const f16x8*)&G[e0];
            const f16x8 b1 = *(const f16x8*)&G[e0 + 32];
            const f16x8 b2 = *(const f16x8*)&G[e0 + 64];
            MFMA16(DA[0][0], AF[0],  b0); MFMA16(DA[0][0], AF[1],  b1);
            MFMA16(DA[0][0], AF[2],  b2);
            MFMA16(DA[1][0], AF[11], b0); MFMA16(DA[1][0], AF[12], b1);
            MFMA16(DA[1][0], AF[13], b2);
        }
        {   // unit 1 (r=2)
            const f16x8 b0 = *(const f16x8*)&G[e1];
            const f16x8 b1 = *(const f16x8*)&G[e1 + 32];
            MFMA16(DA[0][1], AF[3],  b0); MFMA16(DA[0][1], AF[4],  b1);
            MFMA16(DA[1][1], AF[14], b0); MFMA16(DA[1][1], AF[15], b1);
        }
        {   // unit 2 (r=4)
            const f16x8 b0 = *(const f16x8*)&G[e2];
            const f16x8 b1 = *(const f16x8*)&G[e2 + 32];
            MFMA16(DA[0][2], AF[5],  b0); MFMA16(DA[0][2], AF[6],  b1);
            MFMA16(DA[1][2], AF[16], b0); MFMA16(DA[1][2], AF[17], b1);
        }
        {   // unit 3 (r=8)
            const f16x8 b0 = *(const f16x8*)&G[e3];
            const f16x8 b1 = *(const f16x8*)&G[e3 + 32];
            MFMA16(DA[0][3], AF[7],  b0); MFMA16(DA[0][3], AF[8],  b1);
            MFMA16(DA[1][3], AF[18], b0); MFMA16(DA[1][3], AF[19], b1);
        }
        {   // unit 4 (r=16)
            const f16x8 b0 = *(const f16x8*)&G[e4];
            const f16x8 b1 = *(const f16x8*)&G[e4 + 32];
            MFMA16(DA[0][4], AF[9],  b0); MFMA16(DA[0][4], AF[10], b1);
            MFMA16(DA[1][4], AF[20], b0); MFMA16(DA[1][4], AF[21], b1);
        }
        __syncthreads();   // all B-reads done; region becomes D-raw scratch

        // ---- D-raw (stride-5 rows, conflict-free) + gather + skip + store --
        const int t00 = 4 * lane;
        #pragma unroll
        for (int cc = 0; cc < 2; ++cc) {
            #pragma unroll
            for (int u = 0; u < 5; ++u) {
                const int row = ((w * 5 + u) * 64 + lane);
                #pragma unroll
                for (int e = 0; e < 4; ++e)
                    DR[row * 5 + e] = DA[cc][u][e];
            }

            f32x4 acc;
            {   // unit0: r=1
                const int sL  = (lane >> 2) + 16 * (lane & 3);
                const int row = (w * 5 + 0) * 64 + sL;
                acc[0] = DR[row * 5 + 0]; acc[1] = DR[row * 5 + 1];
                acc[2] = DR[row * 5 + 2]; acc[3] = DR[row * 5 + 3];
            }
            {   // unit1: r=2
                const int da = (2 * lane) & 15;
                const int uu = lane >> 3;
                const int L  = 2 * uu + 16 * (da >> 2);
                const int bi = ((w * 5 + 1) * 64 + L) * 5 + (da & 3);
                const f32x2 P = *(const f32x2*)&DR[bi];
                const f32x2 Q = *(const f32x2*)&DR[bi + 5];
                acc[0] += P.x; acc[1] += Q.x; acc[2] += P.y; acc[3] += Q.y;
            }
            {   // unit2: r=4
                const int de = lane & 15;
                const int uu = lane >> 4;
                const int L0 = 4 * uu + 16 * (de >> 2);
                const int rb = (w * 5 + 2) * 64 + L0;
                #pragma unroll
                for (int e = 0; e < 4; ++e)
                    acc[e] += DR[(rb + e) * 5 + (de & 3)];
            }
            {   // unit3: r=8
                const int de = (lane >> 1) & 15;
                const int uu = lane >> 5;
                const int L0 = 8 * uu + 4 * (lane & 1) + 16 * (de >> 2);
                const int rb = (w * 5 + 3) * 64 + L0;
                #pragma unroll
                for (int e = 0; e < 4; ++e)
                    acc[e] += DR[(rb + e) * 5 + (de & 3)];
            }
            {   // unit4: r=16
                const int de = (lane >> 2) & 15;
                const int L0 = 4 * (lane & 3) + 16 * (de >> 2);
                const int rb = (w * 5 + 4) * 64 + L0;
                #pragma unroll
                for (int e = 0; e < 4; ++e)
                    acc[e] += DR[(rb + e) * 5 + (de & 3)];
            }

            const int c  = cpair * 2 + cc;
            const int gt = t0s + 256 * w + t00;
            const f32x4 xv = *(const f32x4*)(xrow + gt);
            acc += xv * (cc == 0 ? dC0 : dC1);
            *(f32x4*)(out + ((size_t)(b * NH + h) * 4 + c) * LEN + gt) = acc;
        }
    }
}

extern "C" void kernel_launch(void* const* d_in, const int* in_sizes, int n_in,
                              void* d_out, int out_size, void* d_ws, size_t ws_size,
                              hipStream_t stream)
{
    const float* x       = (const float*)d_in[0];
    const float* kernels = (const float*)d_in[1];
    const float* D       = (const float*)d_in[2];
    float*       out     = (float*)d_out;
    unsigned short* wtab = (unsigned short*)d_ws;   // 1.31 MB

    build_wgt_kernel<<<256, 64, 0, stream>>>(kernels, wtab);
    conv_kernel<<<dim3(2, NH, NB), 256, 0, stream>>>(x, wtab, D, out);
}

// Round 9
// 244.344 us; speedup vs baseline: 1.6395x; 1.6395x over previous
//
#include <hip/hip_runtime.h>

#define HEADS 4
#define NH    256
#define LEN   4096
#define NB    16
#define TT    1024
#define NSUB  4

typedef float     f32x4 __attribute__((ext_vector_type(4)));
typedef float     f32x2 __attribute__((ext_vector_type(2)));
typedef _Float16  f16x8 __attribute__((ext_vector_type(8)));
typedef unsigned  u32x2 __attribute__((ext_vector_type(2)));
typedef unsigned  u32x4 __attribute__((ext_vector_type(4)));

__device__ __forceinline__ unsigned packh(float a, float b) {
    union { _Float16 h[2]; unsigned u; } z;
    z.h[0] = (_Float16)a; z.h[1] = (_Float16)b;
    return z.u;
}
__device__ __forceinline__ unsigned short h16u(float a) {
    union { _Float16 h; unsigned short u; } z;
    z.h = (_Float16)a; return z.u;
}

// ---------------------------------------------------------------------------
// Weight table (verified R7): per (h,c,unit): Prev[y] = w_u[95-y], f16.
// ---------------------------------------------------------------------------
__global__ __launch_bounds__(64) void build_wgt_kernel(
    const float* __restrict__ kernels, unsigned short* __restrict__ wtab)
{
    const int h    = blockIdx.x;
    const int lane = threadIdx.x;

    float ssum[4] = {0.f, 0.f, 0.f, 0.f};
    #pragma unroll
    for (int q = 0; q < 3; ++q) {
        const int tap = lane + q * 64;
        const int i = tap >> 5;
        const int j = tap & 31;
        const float scale = (float)(1 << (5 - i));
        const float repf  = (float)(i == 0 ? 1 : (1 << (i - 1)));
        #pragma unroll
        for (int c = 0; c < 4; ++c) {
            const float kv = kernels[(((i * HEADS) + c) * NH + h) * 32 + j];
            const float v  = kv * scale;
            ssum[c] += v * v * repf;
        }
    }
    #pragma unroll
    for (int off = 32; off > 0; off >>= 1) {
        #pragma unroll
        for (int c = 0; c < 4; ++c) ssum[c] += __shfl_xor(ssum[c], off);
    }
    float inv[4];
    #pragma unroll
    for (int c = 0; c < 4; ++c) inv[c] = 1.0f / sqrtf(ssum[c]);

    for (int it = 0; it < 40; ++it) {
        const int idx = it * 64 + lane;
        const int c   = idx / 640;
        const int rem = idx - c * 640;
        const int u   = rem >> 7;
        const int y   = rem & 127;
        const int j   = 95 - y;
        const int J   = (u == 0) ? 64 : 32;
        float val = 0.f;
        if (j >= 0 && j < J) {
            int s, tp;
            if (u == 0) { s = (j < 32) ? 0 : 1; tp = j & 31; }
            else        { s = u + 1;            tp = j;      }
            val = kernels[((s * HEADS + c) * NH + h) * 32 + tp]
                  * (float)(1 << (5 - s)) * inv[c];
        }
        wtab[((h * 4 + c) * 5 + u) * 128 + y] = h16u(val);
    }
}

// ---------------------------------------------------------------------------
// MFMA conv kernel (structure verified R7/R8).  Grid (2,256,16), 4 waves.
// G arrays bank-deconflicted via per-array XOR swizzle (both read & write);
// epilogue D-scratch stride-5 rows (conflict-free, verified R8).
// ---------------------------------------------------------------------------
// G array BYTE offsets in SM
#define G1B   0
#define G2B   4160
#define G4B   8256
#define G8B   12352
#define G16B  16448
#define SMBYTES 25600        // max(20544 G bytes, 1280 rows * 5 f32 * 4)

// XOR-swizzle: inject high column bits into bank field (bits >=4 only).
#define SWZ(BASE, OFF, SH, MSK) \
    ((char*)SM + (BASE) + ((OFF) ^ ((((OFF) >> (SH)) & (MSK)) << 4)))

#define MFMA16(acc, a, bb) \
    (acc) = __builtin_amdgcn_mfma_f32_16x16x32_f16((a), (bb), (acc), 0, 0, 0)

__global__ __launch_bounds__(256, 2) void conv_kernel(
    const float*           __restrict__ x,
    const unsigned short*  __restrict__ wtab,
    const float*           __restrict__ Dp,
    float*                 __restrict__ out)
{
    __shared__ __align__(16) unsigned char SM[SMBYTES];
    float* DR = (float*)SM;

    const int cpair = blockIdx.x;
    const int h     = blockIdx.y;
    const int b     = blockIdx.z;
    const int tid   = threadIdx.x;
    const int w     = tid >> 6;
    const int lane  = tid & 63;
    const int dd    = lane & 15;
    const int qq    = lane >> 4;

    const float* xrow = x + ((size_t)(b * NH + h)) * LEN;

    // ---- A-fragments: 22 x f16x8 from global ushort loads ----
    f16x8 AF[22];
    #pragma unroll
    for (int cc = 0; cc < 2; ++cc) {
        const int c = cpair * 2 + cc;
        const unsigned short* wpc = wtab + (size_t)((h * 4 + c) * 5) * 128;
        #pragma unroll
        for (int u = 0; u < 5; ++u) {
            const int J   = (u == 0) ? 64 : 32;
            const int nM  = (u == 0) ? 3 : 2;
            const int bse = (u == 0) ? 0 : (2 * u + 1);
            const unsigned short* wp = wpc + u * 128;
            #pragma unroll
            for (int m = 0; m < 3; ++m) {
                if (m < nM) {
                    const int y0 = 95 - dd - J + 32 * m + 8 * qq;
                    u32x4 dw;
                    #pragma unroll
                    for (int d = 0; d < 4; ++d)
                        dw[d] = (unsigned)wp[y0 + 2 * d]
                              | ((unsigned)wp[y0 + 2 * d + 1] << 16);
                    AF[cc * 11 + bse + m] = __builtin_bit_cast(f16x8, dw);
                }
            }
        }
    }

    const float dC0 = Dp[(cpair * 2 + 0) * NH + h];
    const float dC1 = Dp[(cpair * 2 + 1) * NH + h];

    // ---- B-fragment base BYTE offsets (array-local) per unit ----
    const int kap = 16 * w + dd;
    const int E0B = 32 * kap + 1920 + 16 * qq;
    const int E1B = 2048 * (kap & 1)  + 32 * (kap >> 1) + 896 + 16 * qq;
    const int E2B = 1024 * (kap & 3)  + 32 * (kap >> 2) + 384 + 16 * qq;
    const int E3B = 512  * (kap & 7)  + 32 * (kap >> 3) + 128 + 16 * qq;
    const int E4B = 256  * (kap & 15) + 32 * (kap >> 4)       + 16 * qq;

    for (int st = 0; st < NSUB; ++st) {
        const int t0s = st * TT;
        __syncthreads();   // G/D region reuse across subtiles

        // ---- prefix chain (register doubling) + swizzled f16 G-writes ----
        {
            const int bg = t0s - 544 + 8 * tid;
            float v[40];
            #pragma unroll
            for (int blk = 0; blk < 10; ++blk) {
                const int g = bg + 4 * blk;
                f32x4 t;
                if (g >= 0 && g + 3 < LEN) {
                    t = *(const f32x4*)(xrow + g);
                } else {
                    #pragma unroll
                    for (int e = 0; e < 4; ++e) {
                        const int gg = g + e;
                        t[e] = (gg >= 0 && gg < LEN) ? xrow[gg] : 0.f;
                    }
                }
                v[4 * blk] = t.x; v[4 * blk + 1] = t.y;
                v[4 * blk + 2] = t.z; v[4 * blk + 3] = t.w;
            }
            {   // G1 = x (f16), 16B per thread at byte 16*tid
                u32x4 px;
                px[0] = packh(v[32], v[33]); px[1] = packh(v[34], v[35]);
                px[2] = packh(v[36], v[37]); px[3] = packh(v[38], v[39]);
                *(u32x4*)SWZ(G1B, 16 * tid, 7, 1) = px;
            }
            if (tid < 4)
                *(u32x4*)SWZ(G1B, 4096 + 16 * tid, 7, 1) = (u32x4){0, 0, 0, 0};

            #pragma unroll
            for (int j = 39; j >= 2; --j) v[j] += v[j - 1];      // W2
            #pragma unroll
            for (int ph = 0; ph < 2; ++ph) {
                u32x2 pw;
                pw.x = packh(v[32 + ph], v[34 + ph]);
                pw.y = packh(v[36 + ph], v[38 + ph]);
                *(u32x2*)SWZ(G2B, 2048 * ph + 8 * tid, 7, 1) = pw;
            }
            #pragma unroll
            for (int j = 39; j >= 4; --j) v[j] += v[j - 2];      // W4
            #pragma unroll
            for (int ph = 0; ph < 4; ++ph)
                *(unsigned*)SWZ(G4B, 1024 * ph + 4 * tid, 10, 1) =
                    packh(v[32 + ph], v[36 + ph]);
            #pragma unroll
            for (int j = 39; j >= 8; --j) v[j] += v[j - 4];      // W8
            #pragma unroll
            for (int e = 0; e < 8; ++e)
                *(unsigned short*)SWZ(G8B, 512 * e + 2 * tid, 9, 7) =
                    h16u(v[32 + e]);
            #pragma unroll
            for (int j = 39; j >= 16; --j) v[j] += v[j - 8];     // W16
            #pragma unroll
            for (int e = 0; e < 8; ++e) {
                const int E = 8 * (tid & 1) + e;
                *(unsigned short*)SWZ(G16B, 256 * E + 2 * (tid >> 1), 8, 7) =
                    h16u(v[32 + e]);
            }
        }
        __syncthreads();

        // ---- MFMA phase ----
        f32x4 DA[2][5];
        #pragma unroll
        for (int cc = 0; cc < 2; ++cc)
            #pragma unroll
            for (int u = 0; u < 5; ++u) DA[cc][u] = (f32x4){0.f, 0.f, 0.f, 0.f};

        {   // unit 0 (r=1, K=96)
            const f16x8 b0 = *(const f16x8*)SWZ(G1B, E0B,       7, 1);
            const f16x8 b1 = *(const f16x8*)SWZ(G1B, E0B + 64,  7, 1);
            const f16x8 b2 = *(const f16x8*)SWZ(G1B, E0B + 128, 7, 1);
            MFMA16(DA[0][0], AF[0],  b0); MFMA16(DA[0][0], AF[1],  b1);
            MFMA16(DA[0][0], AF[2],  b2);
            MFMA16(DA[1][0], AF[11], b0); MFMA16(DA[1][0], AF[12], b1);
            MFMA16(DA[1][0], AF[13], b2);
        }
        {   // unit 1 (r=2)
            const f16x8 b0 = *(const f16x8*)SWZ(G2B, E1B,      7, 1);
            const f16x8 b1 = *(const f16x8*)SWZ(G2B, E1B + 64, 7, 1);
            MFMA16(DA[0][1], AF[3],  b0); MFMA16(DA[0][1], AF[4],  b1);
            MFMA16(DA[1][1], AF[14], b0); MFMA16(DA[1][1], AF[15], b1);
        }
        {   // unit 2 (r=4)
            const f16x8 b0 = *(const f16x8*)SWZ(G4B, E2B,      10, 1);
            const f16x8 b1 = *(const f16x8*)SWZ(G4B, E2B + 64, 10, 1);
            MFMA16(DA[0][2], AF[5],  b0); MFMA16(DA[0][2], AF[6],  b1);
            MFMA16(DA[1][2], AF[16], b0); MFMA16(DA[1][2], AF[17], b1);
        }
        {   // unit 3 (r=8)
            const f16x8 b0 = *(const f16x8*)SWZ(G8B, E3B,      9, 7);
            const f16x8 b1 = *(const f16x8*)SWZ(G8B, E3B + 64, 9, 7);
            MFMA16(DA[0][3], AF[7],  b0); MFMA16(DA[0][3], AF[8],  b1);
            MFMA16(DA[1][3], AF[18], b0); MFMA16(DA[1][3], AF[19], b1);
        }
        {   // unit 4 (r=16)
            const f16x8 b0 = *(const f16x8*)SWZ(G16B, E4B,      8, 7);
            const f16x8 b1 = *(const f16x8*)SWZ(G16B, E4B + 64, 8, 7);
            MFMA16(DA[0][4], AF[9],  b0); MFMA16(DA[0][4], AF[10], b1);
            MFMA16(DA[1][4], AF[20], b0); MFMA16(DA[1][4], AF[21], b1);
        }
        __syncthreads();   // B-reads done; region becomes D-raw scratch

        // ---- D-raw (stride-5 rows, conflict-free) + gather + skip + store --
        const int t00 = 4 * lane;
        #pragma unroll
        for (int cc = 0; cc < 2; ++cc) {
            #pragma unroll
            for (int u = 0; u < 5; ++u) {
                const int row = ((w * 5 + u) * 64 + lane);
                #pragma unroll
                for (int e = 0; e < 4; ++e)
                    DR[row * 5 + e] = DA[cc][u][e];
            }

            f32x4 acc;
            {   // unit0: r=1
                const int sL  = (lane >> 2) + 16 * (lane & 3);
                const int row = (w * 5 + 0) * 64 + sL;
                acc[0] = DR[row * 5 + 0]; acc[1] = DR[row * 5 + 1];
                acc[2] = DR[row * 5 + 2]; acc[3] = DR[row * 5 + 3];
            }
            {   // unit1: r=2
                const int da = (2 * lane) & 15;
                const int uu = lane >> 3;
                const int L  = 2 * uu + 16 * (da >> 2);
                const int bi = ((w * 5 + 1) * 64 + L) * 5 + (da & 3);
                const f32x2 P = *(const f32x2*)&DR[bi];
                const f32x2 Q = *(const f32x2*)&DR[bi + 5];
                acc[0] += P.x; acc[1] += Q.x; acc[2] += P.y; acc[3] += Q.y;
            }
            {   // unit2: r=4
                const int de = lane & 15;
                const int uu = lane >> 4;
                const int L0 = 4 * uu + 16 * (de >> 2);
                const int rb = (w * 5 + 2) * 64 + L0;
                #pragma unroll
                for (int e = 0; e < 4; ++e)
                    acc[e] += DR[(rb + e) * 5 + (de & 3)];
            }
            {   // unit3: r=8
                const int de = (lane >> 1) & 15;
                const int uu = lane >> 5;
                const int L0 = 8 * uu + 4 * (lane & 1) + 16 * (de >> 2);
                const int rb = (w * 5 + 3) * 64 + L0;
                #pragma unroll
                for (int e = 0; e < 4; ++e)
                    acc[e] += DR[(rb + e) * 5 + (de & 3)];
            }
            {   // unit4: r=16
                const int de = (lane >> 2) & 15;
                const int L0 = 4 * (lane & 3) + 16 * (de >> 2);
                const int rb = (w * 5 + 4) * 64 + L0;
                #pragma unroll
                for (int e = 0; e < 4; ++e)
                    acc[e] += DR[(rb + e) * 5 + (de & 3)];
            }

            const int c  = cpair * 2 + cc;
            const int gt = t0s + 256 * w + t00;
            const f32x4 xv = *(const f32x4*)(xrow + gt);
            acc += xv * (cc == 0 ? dC0 : dC1);
            *(f32x4*)(out + ((size_t)(b * NH + h) * 4 + c) * LEN + gt) = acc;
        }
    }
}

extern "C" void kernel_launch(void* const* d_in, const int* in_sizes, int n_in,
                              void* d_out, int out_size, void* d_ws, size_t ws_size,
                              hipStream_t stream)
{
    const float* x       = (const float*)d_in[0];
    const float* kernels = (const float*)d_in[1];
    const float* D       = (const float*)d_in[2];
    float*       out     = (float*)d_out;
    unsigned short* wtab = (unsigned short*)d_ws;   // 1.31 MB

    build_wgt_kernel<<<256, 64, 0, stream>>>(kernels, wtab);
    conv_kernel<<<dim3(2, NH, NB), 256, 0, stream>>>(x, wtab, D, out);
}

// Round 10
// 235.458 us; speedup vs baseline: 1.7013x; 1.0377x over previous
//
#include <hip/hip_runtime.h>

#define HEADS 4
#define NH    256
#define LEN   4096
#define NB    16
#define TT    1024
#define NSUB  4

typedef float     f32x4 __attribute__((ext_vector_type(4)));
typedef float     f32x2 __attribute__((ext_vector_type(2)));
typedef _Float16  f16x2 __attribute__((ext_vector_type(2)));
typedef _Float16  f16x8 __attribute__((ext_vector_type(8)));
typedef unsigned  u32x2 __attribute__((ext_vector_type(2)));
typedef unsigned  u32x4 __attribute__((ext_vector_type(4)));

__device__ __forceinline__ unsigned packh(float a, float b) {
    union { _Float16 h[2]; unsigned u; } z;
    z.h[0] = (_Float16)a; z.h[1] = (_Float16)b;
    return z.u;
}
__device__ __forceinline__ unsigned short h16u(float a) {
    union { _Float16 h; unsigned short u; } z;
    z.h = (_Float16)a; return z.u;
}
__device__ __forceinline__ float lo16(unsigned u) {
    return (float)__builtin_bit_cast(f16x2, u)[0];
}
__device__ __forceinline__ float hi16(unsigned u) {
    return (float)__builtin_bit_cast(f16x2, u)[1];
}

// ---------------------------------------------------------------------------
// Weight table (verified R7): per (h,c,unit): Prev[y] = w_u[95-y], f16.
// ---------------------------------------------------------------------------
__global__ __launch_bounds__(64) void build_wgt_kernel(
    const float* __restrict__ kernels, unsigned short* __restrict__ wtab)
{
    const int h    = blockIdx.x;
    const int lane = threadIdx.x;

    float ssum[4] = {0.f, 0.f, 0.f, 0.f};
    #pragma unroll
    for (int q = 0; q < 3; ++q) {
        const int tap = lane + q * 64;
        const int i = tap >> 5;
        const int j = tap & 31;
        const float scale = (float)(1 << (5 - i));
        const float repf  = (float)(i == 0 ? 1 : (1 << (i - 1)));
        #pragma unroll
        for (int c = 0; c < 4; ++c) {
            const float kv = kernels[(((i * HEADS) + c) * NH + h) * 32 + j];
            const float v  = kv * scale;
            ssum[c] += v * v * repf;
        }
    }
    #pragma unroll
    for (int off = 32; off > 0; off >>= 1) {
        #pragma unroll
        for (int c = 0; c < 4; ++c) ssum[c] += __shfl_xor(ssum[c], off);
    }
    float inv[4];
    #pragma unroll
    for (int c = 0; c < 4; ++c) inv[c] = 1.0f / sqrtf(ssum[c]);

    for (int it = 0; it < 40; ++it) {
        const int idx = it * 64 + lane;
        const int c   = idx / 640;
        const int rem = idx - c * 640;
        const int u   = rem >> 7;
        const int y   = rem & 127;
        const int j   = 95 - y;
        const int J   = (u == 0) ? 64 : 32;
        float val = 0.f;
        if (j >= 0 && j < J) {
            int s, tp;
            if (u == 0) { s = (j < 32) ? 0 : 1; tp = j & 31; }
            else        { s = u + 1;            tp = j;      }
            val = kernels[((s * HEADS + c) * NH + h) * 32 + tp]
                  * (float)(1 << (5 - s)) * inv[c];
        }
        wtab[((h * 4 + c) * 5 + u) * 128 + y] = h16u(val);
    }
}

// ---------------------------------------------------------------------------
// MFMA conv kernel (structure verified R7/R9).  Grid (2,256,16), 4 waves.
// G arrays XOR-swizzled (verified R9); epilogue single-pass with the two
// heads PACKED as f16 pairs per dword (halves epilogue LDS traffic).
// ---------------------------------------------------------------------------
#define G1B   0
#define G2B   4160
#define G4B   8256
#define G8B   12352
#define G16B  16448
#define SMBYTES 25600        // max(20544 G bytes, 1280 rows * 5 dwords * 4)

#define SWZ(BASE, OFF, SH, MSK) \
    ((char*)SM + (BASE) + ((OFF) ^ ((((OFF) >> (SH)) & (MSK)) << 4)))

#define MFMA16(acc, a, bb) \
    (acc) = __builtin_amdgcn_mfma_f32_16x16x32_f16((a), (bb), (acc), 0, 0, 0)

__global__ __launch_bounds__(256, 2) void conv_kernel(
    const float*           __restrict__ x,
    const unsigned short*  __restrict__ wtab,
    const float*           __restrict__ Dp,
    float*                 __restrict__ out)
{
    __shared__ __align__(16) unsigned char SM[SMBYTES];
    unsigned* DR32 = (unsigned*)SM;

    const int cpair = blockIdx.x;
    const int h     = blockIdx.y;
    const int b     = blockIdx.z;
    const int tid   = threadIdx.x;
    const int w     = tid >> 6;
    const int lane  = tid & 63;
    const int dd    = lane & 15;
    const int qq    = lane >> 4;

    const float* xrow = x + ((size_t)(b * NH + h)) * LEN;

    // ---- A-fragments: 22 x f16x8 from global ushort loads ----
    f16x8 AF[22];
    #pragma unroll
    for (int cc = 0; cc < 2; ++cc) {
        const int c = cpair * 2 + cc;
        const unsigned short* wpc = wtab + (size_t)((h * 4 + c) * 5) * 128;
        #pragma unroll
        for (int u = 0; u < 5; ++u) {
            const int J   = (u == 0) ? 64 : 32;
            const int nM  = (u == 0) ? 3 : 2;
            const int bse = (u == 0) ? 0 : (2 * u + 1);
            const unsigned short* wp = wpc + u * 128;
            #pragma unroll
            for (int m = 0; m < 3; ++m) {
                if (m < nM) {
                    const int y0 = 95 - dd - J + 32 * m + 8 * qq;
                    u32x4 dw;
                    #pragma unroll
                    for (int d = 0; d < 4; ++d)
                        dw[d] = (unsigned)wp[y0 + 2 * d]
                              | ((unsigned)wp[y0 + 2 * d + 1] << 16);
                    AF[cc * 11 + bse + m] = __builtin_bit_cast(f16x8, dw);
                }
            }
        }
    }

    const float dC0 = Dp[(cpair * 2 + 0) * NH + h];
    const float dC1 = Dp[(cpair * 2 + 1) * NH + h];

    // ---- B-fragment base BYTE offsets (array-local) per unit ----
    const int kap = 16 * w + dd;
    const int E0B = 32 * kap + 1920 + 16 * qq;
    const int E1B = 2048 * (kap & 1)  + 32 * (kap >> 1) + 896 + 16 * qq;
    const int E2B = 1024 * (kap & 3)  + 32 * (kap >> 2) + 384 + 16 * qq;
    const int E3B = 512  * (kap & 7)  + 32 * (kap >> 3) + 128 + 16 * qq;
    const int E4B = 256  * (kap & 15) + 32 * (kap >> 4)       + 16 * qq;

    for (int st = 0; st < NSUB; ++st) {
        const int t0s = st * TT;
        __syncthreads();   // G/D region reuse across subtiles

        // ---- prefix chain (register doubling) + swizzled f16 G-writes ----
        {
            const int bg = t0s - 544 + 8 * tid;
            float v[40];
            #pragma unroll
            for (int blk = 0; blk < 10; ++blk) {
                const int g = bg + 4 * blk;
                f32x4 t;
                if (g >= 0 && g + 3 < LEN) {
                    t = *(const f32x4*)(xrow + g);
                } else {
                    #pragma unroll
                    for (int e = 0; e < 4; ++e) {
                        const int gg = g + e;
                        t[e] = (gg >= 0 && gg < LEN) ? xrow[gg] : 0.f;
                    }
                }
                v[4 * blk] = t.x; v[4 * blk + 1] = t.y;
                v[4 * blk + 2] = t.z; v[4 * blk + 3] = t.w;
            }
            {   // G1 = x (f16)
                u32x4 px;
                px[0] = packh(v[32], v[33]); px[1] = packh(v[34], v[35]);
                px[2] = packh(v[36], v[37]); px[3] = packh(v[38], v[39]);
                *(u32x4*)SWZ(G1B, 16 * tid, 7, 1) = px;
            }
            if (tid < 4)
                *(u32x4*)SWZ(G1B, 4096 + 16 * tid, 7, 1) = (u32x4){0, 0, 0, 0};

            #pragma unroll
            for (int j = 39; j >= 2; --j) v[j] += v[j - 1];      // W2
            #pragma unroll
            for (int ph = 0; ph < 2; ++ph) {
                u32x2 pw;
                pw.x = packh(v[32 + ph], v[34 + ph]);
                pw.y = packh(v[36 + ph], v[38 + ph]);
                *(u32x2*)SWZ(G2B, 2048 * ph + 8 * tid, 7, 1) = pw;
            }
            #pragma unroll
            for (int j = 39; j >= 4; --j) v[j] += v[j - 2];      // W4
            #pragma unroll
            for (int ph = 0; ph < 4; ++ph)
                *(unsigned*)SWZ(G4B, 1024 * ph + 4 * tid, 10, 1) =
                    packh(v[32 + ph], v[36 + ph]);
            #pragma unroll
            for (int j = 39; j >= 8; --j) v[j] += v[j - 4];      // W8
            #pragma unroll
            for (int e = 0; e < 8; ++e)
                *(unsigned short*)SWZ(G8B, 512 * e + 2 * tid, 9, 7) =
                    h16u(v[32 + e]);
            #pragma unroll
            for (int j = 39; j >= 16; --j) v[j] += v[j - 8];     // W16
            #pragma unroll
            for (int e = 0; e < 8; ++e) {
                const int E = 8 * (tid & 1) + e;
                *(unsigned short*)SWZ(G16B, 256 * E + 2 * (tid >> 1), 8, 7) =
                    h16u(v[32 + e]);
            }
        }
        __syncthreads();

        // ---- MFMA phase ----
        f32x4 DA[2][5];
        #pragma unroll
        for (int cc = 0; cc < 2; ++cc)
            #pragma unroll
            for (int u = 0; u < 5; ++u) DA[cc][u] = (f32x4){0.f, 0.f, 0.f, 0.f};

        {   // unit 0 (r=1, K=96)
            const f16x8 b0 = *(const f16x8*)SWZ(G1B, E0B,       7, 1);
            const f16x8 b1 = *(const f16x8*)SWZ(G1B, E0B + 64,  7, 1);
            const f16x8 b2 = *(const f16x8*)SWZ(G1B, E0B + 128, 7, 1);
            MFMA16(DA[0][0], AF[0],  b0); MFMA16(DA[0][0], AF[1],  b1);
            MFMA16(DA[0][0], AF[2],  b2);
            MFMA16(DA[1][0], AF[11], b0); MFMA16(DA[1][0], AF[12], b1);
            MFMA16(DA[1][0], AF[13], b2);
        }
        {   // unit 1 (r=2)
            const f16x8 b0 = *(const f16x8*)SWZ(G2B, E1B,      7, 1);
            const f16x8 b1 = *(const f16x8*)SWZ(G2B, E1B + 64, 7, 1);
            MFMA16(DA[0][1], AF[3],  b0); MFMA16(DA[0][1], AF[4],  b1);
            MFMA16(DA[1][1], AF[14], b0); MFMA16(DA[1][1], AF[15], b1);
        }
        {   // unit 2 (r=4)
            const f16x8 b0 = *(const f16x8*)SWZ(G4B, E2B,      10, 1);
            const f16x8 b1 = *(const f16x8*)SWZ(G4B, E2B + 64, 10, 1);
            MFMA16(DA[0][2], AF[5],  b0); MFMA16(DA[0][2], AF[6],  b1);
            MFMA16(DA[1][2], AF[16], b0); MFMA16(DA[1][2], AF[17], b1);
        }
        {   // unit 3 (r=8)
            const f16x8 b0 = *(const f16x8*)SWZ(G8B, E3B,      9, 7);
            const f16x8 b1 = *(const f16x8*)SWZ(G8B, E3B + 64, 9, 7);
            MFMA16(DA[0][3], AF[7],  b0); MFMA16(DA[0][3], AF[8],  b1);
            MFMA16(DA[1][3], AF[18], b0); MFMA16(DA[1][3], AF[19], b1);
        }
        {   // unit 4 (r=16)
            const f16x8 b0 = *(const f16x8*)SWZ(G16B, E4B,      8, 7);
            const f16x8 b1 = *(const f16x8*)SWZ(G16B, E4B + 64, 8, 7);
            MFMA16(DA[0][4], AF[9],  b0); MFMA16(DA[0][4], AF[10], b1);
            MFMA16(DA[1][4], AF[20], b0); MFMA16(DA[1][4], AF[21], b1);
        }
        __syncthreads();   // B-reads done; region becomes D-raw scratch

        // ---- single-pass packed epilogue (both heads per dword) ----
        // write: stride-5 dword rows (bank = (5*row+e)%32, conflict-free, R9)
        #pragma unroll
        for (int u = 0; u < 5; ++u) {
            const int row = (w * 5 + u) * 64 + lane;
            #pragma unroll
            for (int e = 0; e < 4; ++e)
                DR32[row * 5 + e] = packh(DA[0][u][e], DA[1][u][e]);
        }

        f32x4 a0, a1;
        {   // unit0: r=1
            const int sL = (lane >> 2) + 16 * (lane & 3);
            const int rb = ((w * 5 + 0) * 64 + sL) * 5;
            #pragma unroll
            for (int e = 0; e < 4; ++e) {
                const unsigned q = DR32[rb + e];
                a0[e] = lo16(q); a1[e] = hi16(q);
            }
        }
        {   // unit1: r=2  (index map verified R9)
            const int da = (2 * lane) & 15;
            const int uu = lane >> 3;
            const int L  = 2 * uu + 16 * (da >> 2);
            const int bi = ((w * 5 + 1) * 64 + L) * 5 + (da & 3);
            const unsigned qa = DR32[bi],     qb = DR32[bi + 1];
            const unsigned qc = DR32[bi + 5], qd = DR32[bi + 6];
            a0[0] += lo16(qa); a1[0] += hi16(qa);
            a0[2] += lo16(qb); a1[2] += hi16(qb);
            a0[1] += lo16(qc); a1[1] += hi16(qc);
            a0[3] += lo16(qd); a1[3] += hi16(qd);
        }
        {   // unit2: r=4
            const int de = lane & 15;
            const int uu = lane >> 4;
            const int L0 = 4 * uu + 16 * (de >> 2);
            const int rb = (w * 5 + 2) * 64 + L0;
            #pragma unroll
            for (int e = 0; e < 4; ++e) {
                const unsigned q = DR32[(rb + e) * 5 + (de & 3)];
                a0[e] += lo16(q); a1[e] += hi16(q);
            }
        }
        {   // unit3: r=8
            const int de = (lane >> 1) & 15;
            const int uu = lane >> 5;
            const int L0 = 8 * uu + 4 * (lane & 1) + 16 * (de >> 2);
            const int rb = (w * 5 + 3) * 64 + L0;
            #pragma unroll
            for (int e = 0; e < 4; ++e) {
                const unsigned q = DR32[(rb + e) * 5 + (de & 3)];
                a0[e] += lo16(q); a1[e] += hi16(q);
            }
        }
        {   // unit4: r=16
            const int de = (lane >> 2) & 15;
            const int L0 = 4 * (lane & 3) + 16 * (de >> 2);
            const int rb = (w * 5 + 4) * 64 + L0;
            #pragma unroll
            for (int e = 0; e < 4; ++e) {
                const unsigned q = DR32[(rb + e) * 5 + (de & 3)];
                a0[e] += lo16(q); a1[e] += hi16(q);
            }
        }

        // ---- skip + store (both heads) ----
        const int gt = t0s + 256 * w + 4 * lane;
        const f32x4 xv = *(const f32x4*)(xrow + gt);
        const size_t ob = ((size_t)(b * NH + h) * 4 + cpair * 2) * LEN + gt;
        *(f32x4*)(out + ob)       = a0 + xv * dC0;
        *(f32x4*)(out + ob + LEN) = a1 + xv * dC1;
    }
}

extern "C" void kernel_launch(void* const* d_in, const int* in_sizes, int n_in,
                              void* d_out, int out_size, void* d_ws, size_t ws_size,
                              hipStream_t stream)
{
    const float* x       = (const float*)d_in[0];
    const float* kernels = (const float*)d_in[1];
    const float* D       = (const float*)d_in[2];
    float*       out     = (float*)d_out;
    unsigned short* wtab = (unsigned short*)d_ws;   // 1.31 MB

    build_wgt_kernel<<<256, 64, 0, stream>>>(kernels, wtab);
    conv_kernel<<<dim3(2, NH, NB), 256, 0, stream>>>(x, wtab, D, out);
}

// Round 11
// 164.941 us; speedup vs baseline: 2.4287x; 1.4275x over previous
//
#include <hip/hip_runtime.h>

#define HEADS 4
#define NH    256
#define LEN   4096
#define NB    16
#define TT    1024
#define NSUB  4

typedef float     f32x4 __attribute__((ext_vector_type(4)));
typedef _Float16  f16x2 __attribute__((ext_vector_type(2)));
typedef _Float16  f16x8 __attribute__((ext_vector_type(8)));
typedef unsigned  u32x2 __attribute__((ext_vector_type(2)));
typedef unsigned  u32x4 __attribute__((ext_vector_type(4)));

__device__ __forceinline__ unsigned packh(float a, float b) {
    union { _Float16 h[2]; unsigned u; } z;
    z.h[0] = (_Float16)a; z.h[1] = (_Float16)b;
    return z.u;
}
__device__ __forceinline__ unsigned short h16u(float a) {
    union { _Float16 h; unsigned short u; } z;
    z.h = (_Float16)a; return z.u;
}
__device__ __forceinline__ float lo16(unsigned u) {
    return (float)__builtin_bit_cast(f16x2, u)[0];
}
__device__ __forceinline__ float hi16(unsigned u) {
    return (float)__builtin_bit_cast(f16x2, u)[1];
}

// ---------------------------------------------------------------------------
// Weight table (verified R7): per (h,c,unit): Prev[y] = w_u[95-y], f16.
// ---------------------------------------------------------------------------
__global__ __launch_bounds__(64) void build_wgt_kernel(
    const float* __restrict__ kernels, unsigned short* __restrict__ wtab)
{
    const int h    = blockIdx.x;
    const int lane = threadIdx.x;

    float ssum[4] = {0.f, 0.f, 0.f, 0.f};
    #pragma unroll
    for (int q = 0; q < 3; ++q) {
        const int tap = lane + q * 64;
        const int i = tap >> 5;
        const int j = tap & 31;
        const float scale = (float)(1 << (5 - i));
        const float repf  = (float)(i == 0 ? 1 : (1 << (i - 1)));
        #pragma unroll
        for (int c = 0; c < 4; ++c) {
            const float kv = kernels[(((i * HEADS) + c) * NH + h) * 32 + j];
            const float v  = kv * scale;
            ssum[c] += v * v * repf;
        }
    }
    #pragma unroll
    for (int off = 32; off > 0; off >>= 1) {
        #pragma unroll
        for (int c = 0; c < 4; ++c) ssum[c] += __shfl_xor(ssum[c], off);
    }
    float inv[4];
    #pragma unroll
    for (int c = 0; c < 4; ++c) inv[c] = 1.0f / sqrtf(ssum[c]);

    for (int it = 0; it < 40; ++it) {
        const int idx = it * 64 + lane;
        const int c   = idx / 640;
        const int rem = idx - c * 640;
        const int u   = rem >> 7;
        const int y   = rem & 127;
        const int j   = 95 - y;
        const int J   = (u == 0) ? 64 : 32;
        float val = 0.f;
        if (j >= 0 && j < J) {
            int s, tp;
            if (u == 0) { s = (j < 32) ? 0 : 1; tp = j & 31; }
            else        { s = u + 1;            tp = j;      }
            val = kernels[((s * HEADS + c) * NH + h) * 32 + tp]
                  * (float)(1 << (5 - s)) * inv[c];
        }
        wtab[((h * 4 + c) * 5 + u) * 128 + y] = h16u(val);
    }
}

// ---------------------------------------------------------------------------
// MFMA conv kernel (structure verified R7-R10).  Grid (2,256,16), 4 waves.
// AF weights staged in LDS (frees ~88 VGPRs -> occupancy);
// sequential per-unit wave-private epilogue (DR 5KB, no 3rd barrier).
// ---------------------------------------------------------------------------
#define AFB   0                 // 22 frags * 64 lanes * 16B = 22528
#define GBASE 22528
#define G1B   (GBASE + 0)
#define G2B   (GBASE + 4160)
#define G4B   (GBASE + 8256)
#define G8B   (GBASE + 12352)
#define G16B  (GBASE + 16448)   // G region ends at GBASE+20544 = 43072
#define DRB   43072             // 4 waves * 64 rows * 5 dwords * 4B = 5120
#define SMBYTES 48192

#define SWZ(BASE, OFF, SH, MSK) \
    ((char*)SM + (BASE) + ((OFF) ^ ((((OFF) >> (SH)) & (MSK)) << 4)))

#define AFRD(F) (*(const f16x8*)((char*)SM + AFB + (F) * 1024 + lane * 16))

#define MFMA16(acc, a, bb) \
    (acc) = __builtin_amdgcn_mfma_f32_16x16x32_f16((a), (bb), (acc), 0, 0, 0)

__global__ __launch_bounds__(256, 3) void conv_kernel(
    const float*           __restrict__ x,
    const unsigned short*  __restrict__ wtab,
    const float*           __restrict__ Dp,
    float*                 __restrict__ out)
{
    __shared__ __align__(16) unsigned char SM[SMBYTES];
    unsigned* DR32 = (unsigned*)(SM + DRB);

    const int cpair = blockIdx.x;
    const int h     = blockIdx.y;
    const int b     = blockIdx.z;
    const int tid   = threadIdx.x;
    const int w     = tid >> 6;
    const int lane  = tid & 63;
    const int dd    = lane & 15;
    const int qq    = lane >> 4;

    const float* xrow = x + ((size_t)(b * NH + h)) * LEN;

    // ---- AF build (wave 0 only): 22 frags -> LDS, one frag at a time ----
    if (w == 0) {
        #pragma unroll
        for (int cc = 0; cc < 2; ++cc) {
            const int c = cpair * 2 + cc;
            const unsigned short* wpc = wtab + (size_t)((h * 4 + c) * 5) * 128;
            #pragma unroll
            for (int u = 0; u < 5; ++u) {
                const int J   = (u == 0) ? 64 : 32;
                const int nM  = (u == 0) ? 3 : 2;
                const int bse = (u == 0) ? 0 : (2 * u + 1);
                const unsigned short* wp = wpc + u * 128;
                #pragma unroll
                for (int m = 0; m < 3; ++m) {
                    if (m < nM) {
                        const int y0 = 95 - dd - J + 32 * m + 8 * qq;
                        u32x4 dw;
                        #pragma unroll
                        for (int d = 0; d < 4; ++d)
                            dw[d] = (unsigned)wp[y0 + 2 * d]
                                  | ((unsigned)wp[y0 + 2 * d + 1] << 16);
                        const int f = cc * 11 + bse + m;
                        *(u32x4*)((char*)SM + AFB + f * 1024 + lane * 16) = dw;
                    }
                }
            }
        }
    }
    // G1 tail pad zeros (persistent region now -> write once)
    if (tid < 4)
        *(u32x4*)SWZ(G1B - GBASE + GBASE, 4096 + 16 * tid, 7, 1) = (u32x4){0,0,0,0};

    const float dC0 = Dp[(cpair * 2 + 0) * NH + h];
    const float dC1 = Dp[(cpair * 2 + 1) * NH + h];

    // ---- B-fragment base BYTE offsets (array-local) per unit ----
    const int kap = 16 * w + dd;
    const int E0B = 32 * kap + 1920 + 16 * qq;
    const int E1B = 2048 * (kap & 1)  + 32 * (kap >> 1) + 896 + 16 * qq;
    const int E2B = 1024 * (kap & 3)  + 32 * (kap >> 2) + 384 + 16 * qq;
    const int E3B = 512  * (kap & 7)  + 32 * (kap >> 3) + 128 + 16 * qq;
    const int E4B = 256  * (kap & 15) + 32 * (kap >> 4)       + 16 * qq;

    for (int st = 0; st < NSUB; ++st) {
        const int t0s = st * TT;
        __syncthreads();   // G rewrite vs prior-subtile B-reads (+ AF ready)

        // ---- prefix chain (register doubling) + swizzled f16 G-writes ----
        {
            const int bg = t0s - 544 + 8 * tid;
            float v[40];
            #pragma unroll
            for (int blk = 0; blk < 10; ++blk) {
                const int g = bg + 4 * blk;
                f32x4 t;
                if (g >= 0 && g + 3 < LEN) {
                    t = *(const f32x4*)(xrow + g);
                } else {
                    #pragma unroll
                    for (int e = 0; e < 4; ++e) {
                        const int gg = g + e;
                        t[e] = (gg >= 0 && gg < LEN) ? xrow[gg] : 0.f;
                    }
                }
                v[4 * blk] = t.x; v[4 * blk + 1] = t.y;
                v[4 * blk + 2] = t.z; v[4 * blk + 3] = t.w;
            }
            {   // G1 = x (f16)
                u32x4 px;
                px[0] = packh(v[32], v[33]); px[1] = packh(v[34], v[35]);
                px[2] = packh(v[36], v[37]); px[3] = packh(v[38], v[39]);
                *(u32x4*)SWZ(G1B, 16 * tid, 7, 1) = px;
            }
            #pragma unroll
            for (int j = 39; j >= 2; --j) v[j] += v[j - 1];      // W2
            #pragma unroll
            for (int ph = 0; ph < 2; ++ph) {
                u32x2 pw;
                pw.x = packh(v[32 + ph], v[34 + ph]);
                pw.y = packh(v[36 + ph], v[38 + ph]);
                *(u32x2*)SWZ(G2B, 2048 * ph + 8 * tid, 7, 1) = pw;
            }
            #pragma unroll
            for (int j = 39; j >= 4; --j) v[j] += v[j - 2];      // W4
            #pragma unroll
            for (int ph = 0; ph < 4; ++ph)
                *(unsigned*)SWZ(G4B, 1024 * ph + 4 * tid, 10, 1) =
                    packh(v[32 + ph], v[36 + ph]);
            #pragma unroll
            for (int j = 39; j >= 8; --j) v[j] += v[j - 4];      // W8
            #pragma unroll
            for (int e = 0; e < 8; ++e)
                *(unsigned short*)SWZ(G8B, 512 * e + 2 * tid, 9, 7) =
                    h16u(v[32 + e]);
            #pragma unroll
            for (int j = 39; j >= 16; --j) v[j] += v[j - 8];     // W16
            #pragma unroll
            for (int e = 0; e < 8; ++e) {
                const int E = 8 * (tid & 1) + e;
                *(unsigned short*)SWZ(G16B, 256 * E + 2 * (tid >> 1), 8, 7) =
                    h16u(v[32 + e]);
            }
        }
        __syncthreads();

        // ---- MFMA phase (A-frags streamed from LDS) ----
        f32x4 DA[2][5];
        #pragma unroll
        for (int cc = 0; cc < 2; ++cc)
            #pragma unroll
            for (int u = 0; u < 5; ++u) DA[cc][u] = (f32x4){0.f, 0.f, 0.f, 0.f};

        {   // unit 0 (r=1, K=96)
            const f16x8 b0 = *(const f16x8*)SWZ(G1B, E0B,       7, 1);
            const f16x8 b1 = *(const f16x8*)SWZ(G1B, E0B + 64,  7, 1);
            const f16x8 b2 = *(const f16x8*)SWZ(G1B, E0B + 128, 7, 1);
            MFMA16(DA[0][0], AFRD(0),  b0); MFMA16(DA[0][0], AFRD(1),  b1);
            MFMA16(DA[0][0], AFRD(2),  b2);
            MFMA16(DA[1][0], AFRD(11), b0); MFMA16(DA[1][0], AFRD(12), b1);
            MFMA16(DA[1][0], AFRD(13), b2);
        }
        {   // unit 1 (r=2)
            const f16x8 b0 = *(const f16x8*)SWZ(G2B, E1B,      7, 1);
            const f16x8 b1 = *(const f16x8*)SWZ(G2B, E1B + 64, 7, 1);
            MFMA16(DA[0][1], AFRD(3),  b0); MFMA16(DA[0][1], AFRD(4),  b1);
            MFMA16(DA[1][1], AFRD(14), b0); MFMA16(DA[1][1], AFRD(15), b1);
        }
        {   // unit 2 (r=4)
            const f16x8 b0 = *(const f16x8*)SWZ(G4B, E2B,      10, 1);
            const f16x8 b1 = *(const f16x8*)SWZ(G4B, E2B + 64, 10, 1);
            MFMA16(DA[0][2], AFRD(5),  b0); MFMA16(DA[0][2], AFRD(6),  b1);
            MFMA16(DA[1][2], AFRD(16), b0); MFMA16(DA[1][2], AFRD(17), b1);
        }
        {   // unit 3 (r=8)
            const f16x8 b0 = *(const f16x8*)SWZ(G8B, E3B,      9, 7);
            const f16x8 b1 = *(const f16x8*)SWZ(G8B, E3B + 64, 9, 7);
            MFMA16(DA[0][3], AFRD(7),  b0); MFMA16(DA[0][3], AFRD(8),  b1);
            MFMA16(DA[1][3], AFRD(18), b0); MFMA16(DA[1][3], AFRD(19), b1);
        }
        {   // unit 4 (r=16)
            const f16x8 b0 = *(const f16x8*)SWZ(G16B, E4B,      8, 7);
            const f16x8 b1 = *(const f16x8*)SWZ(G16B, E4B + 64, 8, 7);
            MFMA16(DA[0][4], AFRD(9),  b0); MFMA16(DA[0][4], AFRD(10), b1);
            MFMA16(DA[1][4], AFRD(20), b0); MFMA16(DA[1][4], AFRD(21), b1);
        }
        // no barrier: DR is a separate wave-private region

        // ---- sequential per-unit epilogue (heads packed per dword) ----
        f32x4 a0 = (f32x4){0.f,0.f,0.f,0.f};
        f32x4 a1 = (f32x4){0.f,0.f,0.f,0.f};

#define DRWRITE(U) do {                                                   \
        const int row_ = w * 64 + lane;                                   \
        _Pragma("unroll")                                                 \
        for (int e = 0; e < 4; ++e)                                       \
            DR32[row_ * 5 + e] = packh(DA[0][U][e], DA[1][U][e]);         \
    } while (0)

        {   // unit0: r=1
            DRWRITE(0);
            const int sL = (lane >> 2) + 16 * (lane & 3);
            const int rb = (w * 64 + sL) * 5;
            #pragma unroll
            for (int e = 0; e < 4; ++e) {
                const unsigned q = DR32[rb + e];
                a0[e] += lo16(q); a1[e] += hi16(q);
            }
        }
        {   // unit1: r=2
            DRWRITE(1);
            const int da = (2 * lane) & 15;
            const int uu = lane >> 3;
            const int L  = 2 * uu + 16 * (da >> 2);
            const int bi = (w * 64 + L) * 5 + (da & 3);
            const unsigned qa = DR32[bi],     qb = DR32[bi + 1];
            const unsigned qc = DR32[bi + 5], qd = DR32[bi + 6];
            a0[0] += lo16(qa); a1[0] += hi16(qa);
            a0[2] += lo16(qb); a1[2] += hi16(qb);
            a0[1] += lo16(qc); a1[1] += hi16(qc);
            a0[3] += lo16(qd); a1[3] += hi16(qd);
        }
        {   // unit2: r=4
            DRWRITE(2);
            const int de = lane & 15;
            const int uu = lane >> 4;
            const int L0 = 4 * uu + 16 * (de >> 2);
            const int rb = w * 64 + L0;
            #pragma unroll
            for (int e = 0; e < 4; ++e) {
                const unsigned q = DR32[(rb + e) * 5 + (de & 3)];
                a0[e] += lo16(q); a1[e] += hi16(q);
            }
        }
        {   // unit3: r=8
            DRWRITE(3);
            const int de = (lane >> 1) & 15;
            const int uu = lane >> 5;
            const int L0 = 8 * uu + 4 * (lane & 1) + 16 * (de >> 2);
            const int rb = w * 64 + L0;
            #pragma unroll
            for (int e = 0; e < 4; ++e) {
                const unsigned q = DR32[(rb + e) * 5 + (de & 3)];
                a0[e] += lo16(q); a1[e] += hi16(q);
            }
        }
        {   // unit4: r=16
            DRWRITE(4);
            const int de = (lane >> 2) & 15;
            const int L0 = 4 * (lane & 3) + 16 * (de >> 2);
            const int rb = w * 64 + L0;
            #pragma unroll
            for (int e = 0; e < 4; ++e) {
                const unsigned q = DR32[(rb + e) * 5 + (de & 3)];
                a0[e] += lo16(q); a1[e] += hi16(q);
            }
        }
#undef DRWRITE

        // ---- skip + store (both heads) ----
        const int gt = t0s + 256 * w + 4 * lane;
        const f32x4 xv = *(const f32x4*)(xrow + gt);
        const size_t ob = ((size_t)(b * NH + h) * 4 + cpair * 2) * LEN + gt;
        *(f32x4*)(out + ob)       = a0 + xv * dC0;
        *(f32x4*)(out + ob + LEN) = a1 + xv * dC1;
    }
}

extern "C" void kernel_launch(void* const* d_in, const int* in_sizes, int n_in,
                              void* d_out, int out_size, void* d_ws, size_t ws_size,
                              hipStream_t stream)
{
    const float* x       = (const float*)d_in[0];
    const float* kernels = (const float*)d_in[1];
    const float* D       = (const float*)d_in[2];
    float*       out     = (float*)d_out;
    unsigned short* wtab = (unsigned short*)d_ws;   // 1.31 MB

    build_wgt_kernel<<<256, 64, 0, stream>>>(kernels, wtab);
    conv_kernel<<<dim3(2, NH, NB), 256, 0, stream>>>(x, wtab, D, out);
}